// Round 1
// baseline (563.786 us; speedup 1.0000x reference)
//
#include <hip/hip_runtime.h>
#include <hip/hip_bf16.h>

// Sizes fixed by the problem
#define T_SEQ 1024

__device__ __forceinline__ float fast_sigmoid(float x) {
    return 1.0f / (1.0f + __expf(-x));
}
__device__ __forceinline__ float fast_tanh(float x) {
    float e = __expf(2.0f * x);
    return 1.0f - 2.0f / (e + 1.0f);
}

// K1: precompute u-dependent parts of both RNN linears (+bias)
// pre_i[k*64+i] = i2h_b[i] + sum_c u[k][c]*i2h_w[i][c]
__global__ __launch_bounds__(256) void k_rnn_pre(
    const float* __restrict__ u,
    const float* __restrict__ i2h_w, const float* __restrict__ i2h_b,
    const float* __restrict__ h2o_w, const float* __restrict__ h2o_b,
    float* __restrict__ pre_i, float* __restrict__ pre_o) {
    int idx = blockIdx.x * 256 + threadIdx.x;   // 0..65535
    int k = idx >> 6, i = idx & 63;
    float a = i2h_b[i], b = h2o_b[i];
#pragma unroll
    for (int c = 0; c < 8; ++c) {
        float uv = u[k * 8 + c];
        a += uv * i2h_w[i * 72 + c];
        b += uv * h2o_w[i * 72 + c];
    }
    pre_i[idx] = a;
    pre_o[idx] = b;
}

// K2: the sequential h-chain. 1 block, 256 threads = 4 waves.
// Wave q computes partial sums over m in [16q,16q+16). hseq[k] = h BEFORE step k (h_0 = 0).
__global__ __launch_bounds__(256) void k_rnn_chain(
    const float* __restrict__ i2h_w,
    const float* __restrict__ pre_i,
    float* __restrict__ hseq) {
    __shared__ float h[64];
    __shared__ float part[4][64];
    int t = threadIdx.x, i = t & 63, q = t >> 6;
    float w[16];
#pragma unroll
    for (int j = 0; j < 16; ++j) w[j] = i2h_w[i * 72 + 8 + 16 * q + j];
    if (q == 0) h[i] = 0.0f;
    float pre_next = (q == 0) ? pre_i[i] : 0.0f;   // pre for k=0
    __syncthreads();
    for (int k = 0; k < T_SEQ; ++k) {
        float pre_cur = pre_next;
        if (q == 0) {
            hseq[k * 64 + i] = h[i];               // carry at step k
            if (k + 1 < T_SEQ) pre_next = pre_i[(k + 1) * 64 + i];  // prefetch
        }
        float acc = 0.0f;
#pragma unroll
        for (int j = 0; j < 16; ++j) acc += w[j] * h[16 * q + j];
        part[q][i] = acc;
        __syncthreads();
        if (q == 0) {
            float s = part[0][i] + part[1][i] + part[2][i] + part[3][i] + pre_cur;
            h[i] = fast_tanh(s);
        }
        __syncthreads();
    }
}

// K3: all RNN outputs in parallel: uout[k][i] = tanh(pre_o[k][i] + sum_m Who[i][m]*hseq[k][m])
__global__ __launch_bounds__(64) void k_rnn_out(
    const float* __restrict__ h2o_w,
    const float* __restrict__ pre_o,
    const float* __restrict__ hseq,
    float* __restrict__ uout) {
    int k = blockIdx.x, i = threadIdx.x;
    __shared__ float hk[64];
    hk[i] = hseq[k * 64 + i];
    __syncthreads();
    float acc = pre_o[k * 64 + i];
#pragma unroll
    for (int m = 0; m < 64; ++m) acc += h2o_w[i * 72 + 8 + m] * hk[m];
    uout[k * 64 + i] = fast_tanh(acc);
}

// ---- K4: fused batch kernel ----
// LDS float offsets (w1 padded 65->68 for 16B-aligned rows; cw stored transposed)
#define L_XW1 0
#define L_XB1 1360
#define L_XW2 1380
#define L_XB2 1780
#define L_XW3 1800
#define L_XB3 3080
#define L_UW1 3144
#define L_UB1 4504
#define L_UW2 4524
#define L_UB2 4924
#define L_UW3 4944
#define L_UB3 6224
#define L_CWT 6288   // cwT[j*64+s] = cw[s*128+j], j in [0,128)
#define L_CB  14480
#define L_TOT 14544  // 58176 bytes

template <int OW1, int OB1, int OW2, int OB2, int OW3, int OB3, int OCWT>
__device__ __forceinline__ void run_branch(const float* __restrict__ sm,
                                           const float* z, float* outacc) {
    float h1[20];
#pragma unroll
    for (int o = 0; o < 20; ++o) {
        float a = sm[OB1 + o];
#pragma unroll
        for (int j = 0; j < 65; ++j) a += z[j] * sm[OW1 + o * 68 + j];
        h1[o] = fast_sigmoid(a);
    }
    float h2[20];
#pragma unroll
    for (int o = 0; o < 20; ++o) {
        float a = sm[OB2 + o];
#pragma unroll
        for (int j = 0; j < 20; ++j) a += h1[j] * sm[OW2 + o * 20 + j];
        h2[o] = fast_sigmoid(a);
    }
    // L3 fused with the final matmul: never materialize sp[64] in registers
#pragma unroll 2
    for (int o = 0; o < 64; ++o) {
        float a = sm[OB3 + o];
#pragma unroll
        for (int j = 0; j < 20; ++j) a += h2[j] * sm[OW3 + o * 20 + j];
        float so = fast_sigmoid(a);
#pragma unroll
        for (int s = 0; s < 64; ++s) outacc[s] += so * sm[OCWT + o * 64 + s];
    }
}

__global__ __launch_bounds__(256) void k_batch(
    const float* __restrict__ t_in, const float* __restrict__ x_in,
    const float* __restrict__ uout,
    const float* __restrict__ xw1, const float* __restrict__ xb1,
    const float* __restrict__ xw2, const float* __restrict__ xb2,
    const float* __restrict__ xw3, const float* __restrict__ xb3,
    const float* __restrict__ uw1, const float* __restrict__ ub1,
    const float* __restrict__ uw2, const float* __restrict__ ub2,
    const float* __restrict__ uw3, const float* __restrict__ ub3,
    const float* __restrict__ cw, const float* __restrict__ cb,
    float* __restrict__ out) {
    __shared__ float sm[L_TOT];
    const int tid = threadIdx.x;
    for (int idx = tid; idx < 1300; idx += 256) {
        int o = idx / 65, j = idx - o * 65;
        sm[L_XW1 + o * 68 + j] = xw1[idx];
        sm[L_UW1 + o * 68 + j] = uw1[idx];
    }
    for (int idx = tid; idx < 400; idx += 256) {
        sm[L_XW2 + idx] = xw2[idx];
        sm[L_UW2 + idx] = uw2[idx];
    }
    for (int idx = tid; idx < 1280; idx += 256) {
        sm[L_XW3 + idx] = xw3[idx];
        sm[L_UW3 + idx] = uw3[idx];
    }
    if (tid < 20) {
        sm[L_XB1 + tid] = xb1[tid]; sm[L_XB2 + tid] = xb2[tid];
        sm[L_UB1 + tid] = ub1[tid]; sm[L_UB2 + tid] = ub2[tid];
    }
    if (tid < 64) {
        sm[L_XB3 + tid] = xb3[tid]; sm[L_UB3 + tid] = ub3[tid];
        sm[L_CB + tid] = cb[tid];
    }
    for (int idx = tid; idx < 8192; idx += 256) {
        int s = idx >> 7, j = idx & 127;
        sm[L_CWT + j * 64 + s] = cw[idx];   // transpose
    }
    __syncthreads();

    const int r = blockIdx.x * 256 + tid;
    float tval = t_in[r];
    float z[65];
    z[0] = tval;
    const float4* xp = reinterpret_cast<const float4*>(x_in + (size_t)r * 64);
#pragma unroll
    for (int v = 0; v < 16; ++v) {
        float4 f = xp[v];
        z[1 + 4 * v + 0] = f.x; z[1 + 4 * v + 1] = f.y;
        z[1 + 4 * v + 2] = f.z; z[1 + 4 * v + 3] = f.w;
    }
    float outacc[64];
#pragma unroll
    for (int s = 0; s < 64; ++s) outacc[s] = sm[L_CB + s];

    // state branch
    run_branch<L_XW1, L_XB1, L_XW2, L_XB2, L_XW3, L_XB3, L_CWT>(sm, z, outacc);

    // gather encoded controls, reuse z[1..64]
    int ti = (int)(tval * 1024.0f);
    ti = min(ti, 1023);
    const float4* ep = reinterpret_cast<const float4*>(uout + ti * 64);
#pragma unroll
    for (int v = 0; v < 16; ++v) {
        float4 f = ep[v];
        z[1 + 4 * v + 0] = f.x; z[1 + 4 * v + 1] = f.y;
        z[1 + 4 * v + 2] = f.z; z[1 + 4 * v + 3] = f.w;
    }
    // control branch (second half of cwT rows)
    run_branch<L_UW1, L_UB1, L_UW2, L_UB2, L_UW3, L_UB3, L_CWT + 4096>(sm, z, outacc);

    float4* op = reinterpret_cast<float4*>(out + (size_t)r * 64);
#pragma unroll
    for (int v = 0; v < 16; ++v) {
        float4 f;
        f.x = outacc[4 * v + 0]; f.y = outacc[4 * v + 1];
        f.z = outacc[4 * v + 2]; f.w = outacc[4 * v + 3];
        op[v] = f;
    }
}

extern "C" void kernel_launch(void* const* d_in, const int* in_sizes, int n_in,
                              void* d_out, int out_size, void* d_ws, size_t ws_size,
                              hipStream_t stream) {
    const float* t     = (const float*)d_in[0];
    const float* x     = (const float*)d_in[1];
    const float* u     = (const float*)d_in[2];
    const float* i2h_w = (const float*)d_in[3];
    const float* i2h_b = (const float*)d_in[4];
    const float* h2o_w = (const float*)d_in[5];
    const float* h2o_b = (const float*)d_in[6];
    const float* xw1 = (const float*)d_in[7];  const float* xb1 = (const float*)d_in[8];
    const float* xw2 = (const float*)d_in[9];  const float* xb2 = (const float*)d_in[10];
    const float* xw3 = (const float*)d_in[11]; const float* xb3 = (const float*)d_in[12];
    const float* uw1 = (const float*)d_in[13]; const float* ub1 = (const float*)d_in[14];
    const float* uw2 = (const float*)d_in[15]; const float* ub2 = (const float*)d_in[16];
    const float* uw3 = (const float*)d_in[17]; const float* ub3 = (const float*)d_in[18];
    const float* cw  = (const float*)d_in[19]; const float* cb  = (const float*)d_in[20];
    float* out = (float*)d_out;

    float* ws    = (float*)d_ws;
    float* pre_i = ws;                 // 65536 floats
    float* pre_o = ws + 65536;         // 65536
    float* hseq  = ws + 131072;        // 65536
    float* uo    = ws + 196608;        // 65536

    int Bv = in_sizes[0];              // 262144

    hipLaunchKernelGGL(k_rnn_pre, dim3(256), dim3(256), 0, stream,
                       u, i2h_w, i2h_b, h2o_w, h2o_b, pre_i, pre_o);
    hipLaunchKernelGGL(k_rnn_chain, dim3(1), dim3(256), 0, stream,
                       i2h_w, pre_i, hseq);
    hipLaunchKernelGGL(k_rnn_out, dim3(T_SEQ), dim3(64), 0, stream,
                       h2o_w, pre_o, hseq, uo);
    hipLaunchKernelGGL(k_batch, dim3(Bv / 256), dim3(256), 0, stream,
                       t, x, uo,
                       xw1, xb1, xw2, xb2, xw3, xb3,
                       uw1, ub1, uw2, ub2, uw3, ub3,
                       cw, cb, out);
}